// Round 7
// baseline (663.068 us; speedup 1.0000x reference)
//
#include <hip/hip_runtime.h>
#include <hip/hip_bf16.h>

// BMMGroupedGEMM: out[e,m,n] = sum_k x[e,m,k] * w[e,n,k], rows m >= m_sizes[e] zeroed.
// E=8, MAX_M=2048, K=2048, N=8192. fp32 in/out.
// Round 7: fuse ds_read + MFMA into ONE barrier-free region so the compiler
// interleaves them (rounds 4-6 had ds_read -> s_barrier -> MFMA: the barrier is a
// scheduling fence, so LDS drain (2304 cyc) and MFMA drain (2483 cyc) serialized
// -- measured wall 4900 cyc/K-tile matches the sum exactly). New phase:
//   vmcnt(4|0); BAR; stage 4 gloads; ldB4+ldA; 32 MFMA   (1 barrier per phase)
// Ring retimed: stage@(t,kh) -> [b^1][kh] (tile t+1, same kh), last read at
// (t-1,kh) = >=2 barriers before issue; landed check via vmcnt(4) two phases later.

#define NE   8
#define MAXM 2048
#define KD   2048
#define ND   8192

#define BM   256
#define BN   256
#define BK   64
#define NTS  (KD/BK)     // 32 K-tiles per output tile

typedef __attribute__((ext_vector_type(8))) short          short8;
typedef __attribute__((ext_vector_type(8))) unsigned short us8;
typedef __attribute__((ext_vector_type(4))) float          f32x4;
typedef __attribute__((ext_vector_type(4))) unsigned short us4;

__device__ __forceinline__ unsigned short f2bf(float f) {
    union { float f; unsigned u; } v; v.f = f;
    unsigned u = v.u;
    return (unsigned short)((u + 0x7FFFu + ((u >> 16) & 1u)) >> 16);  // RNE
}

__device__ __forceinline__ void gload16(const void* g, void* l) {
    __builtin_amdgcn_global_load_lds(
        (const __attribute__((address_space(1))) void*)g,
        (__attribute__((address_space(3))) void*)l, 16, 0, 0);
}

// ---------------- Pass 1a: fp32 -> bf16 for W (full) ----------------
__global__ __launch_bounds__(256) void cvt_kernel(const float* __restrict__ src,
                                                  unsigned short* __restrict__ dst,
                                                  int n8) {
    int i = blockIdx.x * blockDim.x + threadIdx.x;
    int stride = gridDim.x * blockDim.x;
    for (; i < n8; i += stride) {
        const f32x4* s = (const f32x4*)(src + (size_t)i * 8);
        f32x4 a = s[0], b = s[1];
        us8 v = (us8){f2bf(a[0]), f2bf(a[1]), f2bf(a[2]), f2bf(a[3]),
                      f2bf(b[0]), f2bf(b[1]), f2bf(b[2]), f2bf(b[3])};
        *(us8*)(dst + (size_t)i * 8) = v;
    }
}

// ---------------- Pass 1b: fp32 -> bf16 for X, masked rows skipped ----------------
__global__ __launch_bounds__(256) void cvt_x_kernel(const float* __restrict__ src,
                                                    unsigned short* __restrict__ dst,
                                                    const int* __restrict__ ms) {
    int bid = blockIdx.x;            // E*MAXM rows
    int e = bid >> 11, m = bid & 2047;
    if (m >= ms[e]) return;
    const float* s = src + ((size_t)e * MAXM + m) * KD;
    unsigned short* d = dst + ((size_t)e * MAXM + m) * KD;
    int t = threadIdx.x;
    const f32x4* s4 = (const f32x4*)(s + t * 8);
    f32x4 a = s4[0], b = s4[1];
    us8 v = (us8){f2bf(a[0]), f2bf(a[1]), f2bf(a[2]), f2bf(a[3]),
                  f2bf(b[0]), f2bf(b[1]), f2bf(b[2]), f2bf(b[3])};
    *(us8*)(d + t * 8) = v;
}

// ---------------- Pass 2: persistent fused-phase 256x256 bf16 GEMM ----------------
// LDS: A[buf][kh] 256x32 bf16 (16KB) x4 = 64KB; B same = 64KB. Total 128KB.
// Read swizzle slot = kg ^ ((row>>1)&3); write side via pre-swizzled GLOBAL source.
//
// Phase (t, kh), buf b = t&1:
//   vmcnt(vm4?4:0); BAR;
//   stage([b^1][kh], tile t+1, kh)  (4 gloads, guarded)
//   ldB4 + ldA + 32 MFMA            (one region: compiler interleaves lgkmcnt)
// Ledger: entering (t,kh): outstanding = stage@prev-2-phases(4) + stage@prev(4);
// vmcnt(4) drains the older group = this phase's region. vm4 false only when the
// previous phase didn't stage (last tile of last slot). Region safety: stage
// target [b^1][kh] last read at (t-1,kh); >=1 barrier (at (t,0)) before issue;
// ds_read data consumption completes before the wave passes the next barrier.
__global__ __launch_bounds__(512, 2) void ggemm_pers(
    const unsigned short* __restrict__ xb,  // [E][MAXM][KD] bf16
    const unsigned short* __restrict__ wb,  // [E][ND][KD]  bf16
    const int*   __restrict__ ms,
    float*       __restrict__ out)          // [E][MAXM][ND] fp32
{
    int p   = blockIdx.x;          // 256 blocks, 1 per CU
    int xcd = p & 7;
    int jj  = p >> 3;              // 0..31 within XCD
    int tid = threadIdx.x;

    __shared__ int s_live[8], s_dead[8], s_cnt[2];
    __shared__ unsigned short Ak[2][2][BM * 32];   // 64 KB
    __shared__ unsigned short Bk[2][2][BN * 32];   // 64 KB

    // Per-XCD work list, expert-major (round 6; balanced + supertile locality).
    if (tid == 0) {
        int nl = 0, nd = 0, cumL = 0, cumD = 0, il = jj, id = jj;
        #pragma unroll
        for (int e = 0; e < NE; ++e) {
            int L = (ms[e] + 255) >> 8;            // live br rows, 0..8
            int cntL = L << 2, cntD = (8 - L) << 2;
            while (il < cumL + cntL) { int o = il - cumL; s_live[nl++] = (e << 5) | ((o >> 2) << 2) | (o & 3); il += 32; }
            while (id < cumD + cntD) { int o = id - cumD; s_dead[nd++] = (e << 5) | ((L + (o >> 2)) << 2) | (o & 3); id += 32; }
            cumL += cntL; cumD += cntD;
        }
        s_cnt[0] = nl; s_cnt[1] = nd;
    }
    __syncthreads();

    // zero-fill dead tiles
    int ndead = s_cnt[1];
    #pragma unroll 1
    for (int d = 0; d < ndead; ++d) {
        int v = s_dead[d]; int e = v >> 5, br = (v >> 2) & 7, bcl = v & 3;
        float* outE = out + (size_t)e * MAXM * ND;
        int row0 = br * BM, col0 = (xcd * 4 + bcl) * BN;
        f32x4 z = (f32x4){0.f, 0.f, 0.f, 0.f};
        #pragma unroll
        for (int q = 0; q < 32; ++q) {
            int i2 = tid + q * 512;
            int rr = i2 >> 6, cc = (i2 & 63) << 2;
            *(f32x4*)(outE + (size_t)(row0 + rr) * ND + col0 + cc) = z;
        }
    }
    int nlive = s_cnt[0];
    if (nlive == 0) return;

    int wid = tid >> 6, lane = tid & 63;
    int wr = wid >> 2, wc = wid & 3;            // 2x4 wave grid; wave owns 128x64
    int lr = lane & 15, kg = lane >> 4;
    int srow = lane >> 2;
    int ss   = (lane & 3) ^ ((lane >> 3) & 3);  // pre-swizzled source slot (involution)

    auto stageA = [&](int b, int kh, const unsigned short* xP, int kt) {
        #pragma unroll
        for (int q = 0; q < 2; ++q) {
            int blk = wid * 2 + q;
            const unsigned short* src =
                xP + (size_t)(blk * 16 + srow) * KD + kt * BK + kh * 32 + ss * 8;
            gload16(src, (char*)&Ak[b][kh][0] + blk * 1024);
        }
    };
    auto stageB = [&](int b, int kh, const unsigned short* wP, int kt) {
        #pragma unroll
        for (int q = 0; q < 2; ++q) {
            int blk = wid * 2 + q;
            const unsigned short* src =
                wP + (size_t)(blk * 16 + srow) * KD + kt * BK + kh * 32 + ss * 8;
            gload16(src, (char*)&Bk[b][kh][0] + blk * 1024);
        }
    };

    f32x4 acc[8][4];
    #pragma unroll
    for (int mf = 0; mf < 8; ++mf)
        #pragma unroll
        for (int nf = 0; nf < 4; ++nf)
            acc[mf][nf] = (f32x4){0.f, 0.f, 0.f, 0.f};

    // slot metadata (cur / next)
    const unsigned short *xC, *wC, *xN, *wN;
    float *oC, *oN;
    int msC, r0C, c0C, msN, r0N, c0N;
    {
        int v = s_live[0]; int e = v >> 5, br = (v >> 2) & 7, bcl = v & 3;
        r0C = br * BM; c0C = (xcd * 4 + bcl) * BN; msC = ms[e];
        xC = xb + ((size_t)e * MAXM + r0C) * KD;
        wC = wb + ((size_t)e * ND + c0C) * KD;
        oC = out + (size_t)e * MAXM * ND;
    }
    if (nlive > 1) {
        int v = s_live[1]; int e = v >> 5, br = (v >> 2) & 7, bcl = v & 3;
        r0N = br * BM; c0N = (xcd * 4 + bcl) * BN; msN = ms[e];
        xN = xb + ((size_t)e * MAXM + r0N) * KD;
        wN = wb + ((size_t)e * ND + c0N) * KD;
        oN = out + (size_t)e * MAXM * ND;
    } else { xN = xC; wN = wC; oN = oC; msN = msC; r0N = r0C; c0N = c0C; }

    // prologue: stage tile 0 (both k-halves) into buf 0; phase(0,0)'s vmcnt(4)
    // drains the kh0 group (cold stall once per block).
    stageA(0, 0, xC, 0); stageB(0, 0, wC, 0);
    stageA(0, 1, xC, 0); stageB(0, 1, wC, 0);

    #pragma unroll 1
    for (int s = 0; s < nlive; ++s) {
        bool last  = (s + 1 >= nlive);
        bool alive = (r0C + wr * 128) < msC;   // wave-uniform dead-half skip

        // one fused phase; vm4: previous phase staged? stg: this phase stages?
        auto phase = [&](int b, int kh, bool vm4, bool stg,
                         const unsigned short* xS, const unsigned short* wS, int kts) {
            if (vm4) { asm volatile("s_waitcnt vmcnt(4)" ::: "memory"); }
            else     { asm volatile("s_waitcnt vmcnt(0)" ::: "memory"); }
            __builtin_amdgcn_s_barrier();
            if (stg) { stageA(b ^ 1, kh, xS, kts); stageB(b ^ 1, kh, wS, kts); }
            if (alive) {
                short8 a[8], bf[4];
                #pragma unroll
                for (int i = 0; i < 4; ++i) {
                    int row  = wc * 64 + i * 16 + lr;
                    int slot = kg ^ ((row >> 1) & 3);
                    bf[i] = *(const short8*)&Bk[b][kh][row * 32 + slot * 8];
                }
                #pragma unroll
                for (int mf = 0; mf < 8; ++mf) {
                    int row  = wr * 128 + mf * 16 + lr;
                    int slot = kg ^ ((row >> 1) & 3);
                    a[mf] = *(const short8*)&Ak[b][kh][row * 32 + slot * 8];
                }
                // fused: compiler interleaves ds_read completion with MFMA issue
                #pragma unroll
                for (int mf = 0; mf < 8; ++mf)
                    #pragma unroll
                    for (int nf = 0; nf < 4; ++nf)
                        acc[mf][nf] = __builtin_amdgcn_mfma_f32_16x16x32_bf16(a[mf], bf[nf], acc[mf][nf], 0, 0, 0);
            }
        };

        #pragma unroll 1
        for (int kt = 0; kt < NTS; ++kt) {
            int b = kt & 1;
            bool has_next = (kt + 1 < NTS) || (!last);
            const unsigned short* xS = (kt + 1 < NTS) ? xC : xN;
            const unsigned short* wS = (kt + 1 < NTS) ? wC : wN;
            int kts = (kt + 1 < NTS) ? kt + 1 : 0;
            // phase (kt,0): prev phase is (kt-1,1) (or prologue) -> staged unless
            // it was the absolute last staging phase; within any slot it staged.
            phase(b, 0, true, has_next, xS, wS, kts);
            // phase (kt,1): prev phase is (kt,0) -> staged iff has_next.
            phase(b, 1, has_next, has_next, xS, wS, kts);
        }

        // epilogue for this slot (overlaps already-issued next-slot prefetch)
        #pragma unroll
        for (int mf = 0; mf < 8; ++mf) {
            int rbase = r0C + wr * 128 + mf * 16 + kg * 4;
            #pragma unroll
            for (int nf = 0; nf < 4; ++nf) {
                int gc = c0C + wc * 64 + nf * 16 + lr;
                #pragma unroll
                for (int q = 0; q < 4; ++q) {
                    int gr = rbase + q;
                    float v = (gr < msC) ? acc[mf][nf][q] : 0.f;
                    oC[(size_t)gr * ND + gc] = v;
                    acc[mf][nf][q] = 0.f;
                }
            }
        }

        // shift slot window
        xC = xN; wC = wN; oC = oN; msC = msN; r0C = r0N; c0C = c0N;
        if (s + 2 < nlive) {
            int v = s_live[s + 2]; int e = v >> 5, br = (v >> 2) & 7, bcl = v & 3;
            r0N = br * BM; c0N = (xcd * 4 + bcl) * BN; msN = ms[e];
            xN = xb + ((size_t)e * MAXM + r0N) * KD;
            wN = wb + ((size_t)e * ND + c0N) * KD;
            oN = out + (size_t)e * MAXM * ND;
        }
    }
}

// ---------------- Fallback: round-1 fused kernel (used only if ws too small) --------
#define FBM 128
#define FBK 32
#define FTM (MAXM/FBM)
#define FTN (ND/FBM)
#define FNT (KD/FBK)
#define LSTR 40
__global__ __launch_bounds__(256, 2) void ggemm_fused(
    const float* __restrict__ x, const float* __restrict__ w,
    const int* __restrict__ ms, float* __restrict__ out)
{
    int nwg  = gridDim.x;
    int orig = blockIdx.x;
    int cpx  = nwg >> 3;
    int bid  = (orig & 7) * cpx + (orig >> 3);
    int e   = bid / (FTM * FTN);
    int rem = bid % (FTM * FTN);
    int br  = rem % FTM;
    int bc  = rem / FTM;
    int m_size = ms[e];
    int row0 = br * FBM, col0 = bc * FBM;
    float* outE = out + (size_t)e * MAXM * ND;
    int tid = threadIdx.x;

    if (row0 >= m_size) {
        f32x4 z = (f32x4){0.f, 0.f, 0.f, 0.f};
        #pragma unroll
        for (int q = 0; q < 16; ++q) {
            int i2 = tid + q * 256;
            int rr = i2 >> 5, cc = (i2 & 31) << 2;
            *(f32x4*)(outE + (size_t)(row0 + rr) * ND + col0 + cc) = z;
        }
        return;
    }

    const float* xE = x + ((size_t)e * MAXM + row0) * KD;
    const float* wE = w + ((size_t)e * ND   + col0) * KD;

    __shared__ unsigned short As[2][FBM][LSTR];
    __shared__ unsigned short Bs[2][FBM][LSTR];

    int sr  = tid >> 3;
    int sc4 = tid & 7;
    int wid = tid >> 6, lane = tid & 63;
    int wr = wid >> 1, wc = wid & 1;
    int lr = lane & 15, kg = lane >> 4;

    f32x4 acc[4][4];
    #pragma unroll
    for (int m = 0; m < 4; ++m)
        #pragma unroll
        for (int n = 0; n < 4; ++n)
            acc[m][n] = (f32x4){0.f, 0.f, 0.f, 0.f};

    {
        #pragma unroll
        for (int q = 0; q < 4; ++q) {
            int r0 = sr + q * 32;
            f32x4 av = *(const f32x4*)(xE + (size_t)r0 * KD + sc4 * 4);
            f32x4 bv = *(const f32x4*)(wE + (size_t)r0 * KD + sc4 * 4);
            us4 ah = (us4){f2bf(av[0]), f2bf(av[1]), f2bf(av[2]), f2bf(av[3])};
            us4 bh = (us4){f2bf(bv[0]), f2bf(bv[1]), f2bf(bv[2]), f2bf(bv[3])};
            *(us4*)&As[0][r0][sc4 * 4] = ah;
            *(us4*)&Bs[0][r0][sc4 * 4] = bh;
        }
    }
    __syncthreads();

    for (int t = 0; t < FNT; ++t) {
        int cur = t & 1;
        f32x4 av[4], bv[4];
        bool pre = (t + 1 < FNT);
        if (pre) {
            const float* xk = xE + (size_t)(t + 1) * FBK;
            const float* wk = wE + (size_t)(t + 1) * FBK;
            #pragma unroll
            for (int q = 0; q < 4; ++q) {
                int r0 = sr + q * 32;
                av[q] = *(const f32x4*)(xk + (size_t)r0 * KD + sc4 * 4);
                bv[q] = *(const f32x4*)(wk + (size_t)r0 * KD + sc4 * 4);
            }
        }
        short8 a[4], b[4];
        #pragma unroll
        for (int m = 0; m < 4; ++m)
            a[m] = *(const short8*)&As[cur][wr * 64 + m * 16 + lr][kg * 8];
        #pragma unroll
        for (int n = 0; n < 4; ++n)
            b[n] = *(const short8*)&Bs[cur][wc * 64 + n * 16 + lr][kg * 8];
        #pragma unroll
        for (int m = 0; m < 4; ++m)
            #pragma unroll
            for (int n = 0; n < 4; ++n)
                acc[m][n] = __builtin_amdgcn_mfma_f32_16x16x32_bf16(a[m], b[n], acc[m][n], 0, 0, 0);

        if (pre) {
            int nb = cur ^ 1;
            #pragma unroll
            for (int q = 0; q < 4; ++q) {
                int r0 = sr + q * 32;
                us4 ah = (us4){f2bf(av[q][0]), f2bf(av[q][1]), f2bf(av[q][2]), f2bf(av[q][3])};
                us4 bh = (us4){f2bf(bv[q][0]), f2bf(bv[q][1]), f2bf(bv[q][2]), f2bf(bv[q][3])};
                *(us4*)&As[nb][r0][sc4 * 4] = ah;
                *(us4*)&Bs[nb][r0][sc4 * 4] = bh;
            }
        }
        __syncthreads();
    }

    #pragma unroll
    for (int m = 0; m < 4; ++m) {
        int rbase = row0 + wr * 64 + m * 16 + kg * 4;
        #pragma unroll
        for (int n = 0; n < 4; ++n) {
            int gc = col0 + wc * 64 + n * 16 + lr;
            #pragma unroll
            for (int q = 0; q < 4; ++q) {
                int gr = rbase + q;
                float v = (gr < m_size) ? acc[m][n][q] : 0.f;
                outE[(size_t)gr * ND + gc] = v;
            }
        }
    }
}

extern "C" void kernel_launch(void* const* d_in, const int* in_sizes, int n_in,
                              void* d_out, int out_size, void* d_ws, size_t ws_size,
                              hipStream_t stream) {
    const float* x  = (const float*)d_in[0];
    const float* w  = (const float*)d_in[1];
    const int*   ms = (const int*)d_in[2];
    float* out = (float*)d_out;

    const size_t xElems = (size_t)NE * MAXM * KD;   // 33,554,432
    const size_t wElems = (size_t)NE * ND   * KD;   // 134,217,728
    const size_t need   = (xElems + wElems) * 2;    // 335,544,320 B

    if (ws_size >= need) {
        unsigned short* xb = (unsigned short*)d_ws;
        unsigned short* wb = xb + xElems;
        cvt_x_kernel<<<NE * MAXM, 256, 0, stream>>>(x, xb, ms);
        cvt_kernel<<<2048, 256, 0, stream>>>(w, wb, (int)(wElems / 8));
        ggemm_pers<<<256, 512, 0, stream>>>(xb, wb, ms, out);
    } else {
        ggemm_fused<<<dim3(NE * (MAXM/FBM) * (ND/FBM)), dim3(256), 0, stream>>>(x, w, ms, out);
    }
}

// Round 8
// 604.768 us; speedup vs baseline: 1.0964x; 1.0964x over previous
//
#include <hip/hip_runtime.h>
#include <hip/hip_bf16.h>

// BMMGroupedGEMM: out[e,m,n] = sum_k x[e,m,k] * w[e,n,k], rows m >= m_sizes[e] zeroed.
// E=8, MAX_M=2048, K=2048, N=8192. fp32 in/out.
// Round 8: faithful m201-style fine phases: 4 phases/K-tile, each
//   {ds_read 4-8 b128 | stage 2 gloads | BAR | lgkmcnt(0)+sched_barrier |
//    setprio(1) 16 MFMA setprio(0) | [vmcnt(4|0) at p1/p3] | BAR}
// Per-wave lgkmcnt(0) lets early waves MFMA while the LDS port serves later
// waves (round 4-6 coarse 32-MFMA phases serialized the windows; round 7's
// fenceless fusion made the compiler chain read->mfma, VGPR 88, -25%).
// Stage groups G0..G3 = {A.kh0, B.kh0, A.kh1, B.kh1} of tile t+1, one per phase.
// Ledger (instr/wave, 2 per group): entering p0 = 4; p1-end 8 -> vmcnt(4)
// drains (t-1)G2,G3 (read at p2); p3-end 8 -> vmcnt(4) drains (t)G0,G1
// (read at t+1 p0). 3 phases of flight per group. Tails -> vmcnt(0).

#define NE   8
#define MAXM 2048
#define KD   2048
#define ND   8192

#define BM   256
#define BN   256
#define BK   64
#define NTS  (KD/BK)     // 32 K-tiles per output tile

typedef __attribute__((ext_vector_type(8))) short          short8;
typedef __attribute__((ext_vector_type(8))) unsigned short us8;
typedef __attribute__((ext_vector_type(4))) float          f32x4;
typedef __attribute__((ext_vector_type(4))) unsigned short us4;

__device__ __forceinline__ unsigned short f2bf(float f) {
    union { float f; unsigned u; } v; v.f = f;
    unsigned u = v.u;
    return (unsigned short)((u + 0x7FFFu + ((u >> 16) & 1u)) >> 16);  // RNE
}

__device__ __forceinline__ void gload16(const void* g, void* l) {
    __builtin_amdgcn_global_load_lds(
        (const __attribute__((address_space(1))) void*)g,
        (__attribute__((address_space(3))) void*)l, 16, 0, 0);
}

// ---------------- Pass 1a: fp32 -> bf16 for W (full) ----------------
__global__ __launch_bounds__(256) void cvt_kernel(const float* __restrict__ src,
                                                  unsigned short* __restrict__ dst,
                                                  int n8) {
    int i = blockIdx.x * blockDim.x + threadIdx.x;
    int stride = gridDim.x * blockDim.x;
    for (; i < n8; i += stride) {
        const f32x4* s = (const f32x4*)(src + (size_t)i * 8);
        f32x4 a = s[0], b = s[1];
        us8 v = (us8){f2bf(a[0]), f2bf(a[1]), f2bf(a[2]), f2bf(a[3]),
                      f2bf(b[0]), f2bf(b[1]), f2bf(b[2]), f2bf(b[3])};
        *(us8*)(dst + (size_t)i * 8) = v;
    }
}

// ---------------- Pass 1b: fp32 -> bf16 for X, masked rows skipped ----------------
__global__ __launch_bounds__(256) void cvt_x_kernel(const float* __restrict__ src,
                                                    unsigned short* __restrict__ dst,
                                                    const int* __restrict__ ms) {
    int bid = blockIdx.x;            // E*MAXM rows
    int e = bid >> 11, m = bid & 2047;
    if (m >= ms[e]) return;
    const float* s = src + ((size_t)e * MAXM + m) * KD;
    unsigned short* d = dst + ((size_t)e * MAXM + m) * KD;
    int t = threadIdx.x;
    const f32x4* s4 = (const f32x4*)(s + t * 8);
    f32x4 a = s4[0], b = s4[1];
    us8 v = (us8){f2bf(a[0]), f2bf(a[1]), f2bf(a[2]), f2bf(a[3]),
                  f2bf(b[0]), f2bf(b[1]), f2bf(b[2]), f2bf(b[3])};
    *(us8*)(d + t * 8) = v;
}

// ---------------- Pass 2: persistent 4-fine-phase 256x256 bf16 GEMM ----------------
// LDS: A[buf][kh] 256x32 bf16 (16KB) x4 = 64KB; B same = 64KB. Total 128KB.
// Read swizzle slot = kg ^ ((row>>1)&3); write side via pre-swizzled GLOBAL source
// (involution, both-sides rule). Measured conflict-free (rounds 3-6).
__global__ __launch_bounds__(512, 2) void ggemm_pers(
    const unsigned short* __restrict__ xb,  // [E][MAXM][KD] bf16
    const unsigned short* __restrict__ wb,  // [E][ND][KD]  bf16
    const int*   __restrict__ ms,
    float*       __restrict__ out)          // [E][MAXM][ND] fp32
{
    int p   = blockIdx.x;          // 256 blocks, 1 per CU
    int xcd = p & 7;
    int jj  = p >> 3;              // 0..31 within XCD
    int tid = threadIdx.x;

    __shared__ int s_live[8], s_dead[8], s_cnt[2];
    __shared__ unsigned short Ak[2][2][BM * 32];   // 64 KB
    __shared__ unsigned short Bk[2][2][BN * 32];   // 64 KB

    // Per-XCD work list, expert-major (balanced + supertile locality).
    if (tid == 0) {
        int nl = 0, nd = 0, cumL = 0, cumD = 0, il = jj, id = jj;
        #pragma unroll
        for (int e = 0; e < NE; ++e) {
            int L = (ms[e] + 255) >> 8;            // live br rows, 0..8
            int cntL = L << 2, cntD = (8 - L) << 2;
            while (il < cumL + cntL) { int o = il - cumL; s_live[nl++] = (e << 5) | ((o >> 2) << 2) | (o & 3); il += 32; }
            while (id < cumD + cntD) { int o = id - cumD; s_dead[nd++] = (e << 5) | ((L + (o >> 2)) << 2) | (o & 3); id += 32; }
            cumL += cntL; cumD += cntD;
        }
        s_cnt[0] = nl; s_cnt[1] = nd;
    }
    __syncthreads();

    // zero-fill dead tiles
    int ndead = s_cnt[1];
    #pragma unroll 1
    for (int d = 0; d < ndead; ++d) {
        int v = s_dead[d]; int e = v >> 5, br = (v >> 2) & 7, bcl = v & 3;
        float* outE = out + (size_t)e * MAXM * ND;
        int row0 = br * BM, col0 = (xcd * 4 + bcl) * BN;
        f32x4 z = (f32x4){0.f, 0.f, 0.f, 0.f};
        #pragma unroll
        for (int q = 0; q < 32; ++q) {
            int i2 = tid + q * 512;
            int rr = i2 >> 6, cc = (i2 & 63) << 2;
            *(f32x4*)(outE + (size_t)(row0 + rr) * ND + col0 + cc) = z;
        }
    }
    int nlive = s_cnt[0];
    if (nlive == 0) return;

    int wid = tid >> 6, lane = tid & 63;
    int wr = wid >> 2, wc = wid & 3;            // 2x4 wave grid; wave owns 128x64
    int lr = lane & 15, kg = lane >> 4;
    int srow = lane >> 2;
    int ss   = (lane & 3) ^ ((lane >> 3) & 3);  // pre-swizzled source slot (involution)

    auto stageA = [&](int b, int kh, const unsigned short* xP, int kt) {
        #pragma unroll
        for (int q = 0; q < 2; ++q) {
            int blk = wid * 2 + q;
            const unsigned short* src =
                xP + (size_t)(blk * 16 + srow) * KD + kt * BK + kh * 32 + ss * 8;
            gload16(src, (char*)&Ak[b][kh][0] + blk * 1024);
        }
    };
    auto stageB = [&](int b, int kh, const unsigned short* wP, int kt) {
        #pragma unroll
        for (int q = 0; q < 2; ++q) {
            int blk = wid * 2 + q;
            const unsigned short* src =
                wP + (size_t)(blk * 16 + srow) * KD + kt * BK + kh * 32 + ss * 8;
            gload16(src, (char*)&Bk[b][kh][0] + blk * 1024);
        }
    };

    f32x4 acc[8][4];
    #pragma unroll
    for (int mf = 0; mf < 8; ++mf)
        #pragma unroll
        for (int nf = 0; nf < 4; ++nf)
            acc[mf][nf] = (f32x4){0.f, 0.f, 0.f, 0.f};

    // slot metadata (cur / next)
    const unsigned short *xC, *wC, *xN, *wN;
    float *oC, *oN;
    int msC, r0C, c0C, msN, r0N, c0N;
    {
        int v = s_live[0]; int e = v >> 5, br = (v >> 2) & 7, bcl = v & 3;
        r0C = br * BM; c0C = (xcd * 4 + bcl) * BN; msC = ms[e];
        xC = xb + ((size_t)e * MAXM + r0C) * KD;
        wC = wb + ((size_t)e * ND + c0C) * KD;
        oC = out + (size_t)e * MAXM * ND;
    }
    if (nlive > 1) {
        int v = s_live[1]; int e = v >> 5, br = (v >> 2) & 7, bcl = v & 3;
        r0N = br * BM; c0N = (xcd * 4 + bcl) * BN; msN = ms[e];
        xN = xb + ((size_t)e * MAXM + r0N) * KD;
        wN = wb + ((size_t)e * ND + c0N) * KD;
        oN = out + (size_t)e * MAXM * ND;
    } else { xN = xC; wN = wC; oN = oC; msN = msC; r0N = r0C; c0N = c0C; }

    // prologue: stage G0..G3 of tile 0 into buf 0 (8 instr/wave); drain G0,G1.
    stageA(0, 0, xC, 0); stageB(0, 0, wC, 0);
    stageA(0, 1, xC, 0); stageB(0, 1, wC, 0);
    asm volatile("s_waitcnt vmcnt(4)" ::: "memory");
    __builtin_amdgcn_s_barrier();

    #pragma unroll 1
    for (int s = 0; s < nlive; ++s) {
        bool last  = (s + 1 >= nlive);
        bool alive = (r0C + wr * 128) < msC;   // wave-uniform dead-half skip

        #pragma unroll 1
        for (int kt = 0; kt < NTS; ++kt) {
            int b = kt & 1;
            bool stg = (kt + 1 < NTS) || (!last);
            const unsigned short* xS = (kt + 1 < NTS) ? xC : xN;
            const unsigned short* wS = (kt + 1 < NTS) ? wC : wN;
            int kts = (kt + 1 < NTS) ? kt + 1 : 0;

            short8 a[4], bf[4];

            // ======== phase 0: ks0, mh0 — reads B.kh0(4) + A.kh0 rows 0-63(4)
            if (alive) {
                #pragma unroll
                for (int i = 0; i < 4; ++i) {
                    int row  = wc * 64 + i * 16 + lr;
                    int slot = kg ^ ((row >> 1) & 3);
                    bf[i] = *(const short8*)&Bk[b][0][row * 32 + slot * 8];
                }
                #pragma unroll
                for (int i = 0; i < 4; ++i) {
                    int row  = wr * 128 + i * 16 + lr;
                    int slot = kg ^ ((row >> 1) & 3);
                    a[i] = *(const short8*)&Ak[b][0][row * 32 + slot * 8];
                }
            }
            if (stg) stageA(b ^ 1, 0, xS, kts);
            __builtin_amdgcn_s_barrier();
            asm volatile("s_waitcnt lgkmcnt(0)" ::: "memory");
            __builtin_amdgcn_sched_barrier(0);
            __builtin_amdgcn_s_setprio(1);
            if (alive) {
                #pragma unroll
                for (int i = 0; i < 4; ++i)
                    #pragma unroll
                    for (int nf = 0; nf < 4; ++nf)
                        acc[i][nf] = __builtin_amdgcn_mfma_f32_16x16x32_bf16(a[i], bf[nf], acc[i][nf], 0, 0, 0);
            }
            __builtin_amdgcn_s_setprio(0);
            __builtin_amdgcn_s_barrier();

            // ======== phase 1: ks0, mh1 — reads A.kh0 rows 64-127(4); bf reused
            if (alive) {
                #pragma unroll
                for (int i = 0; i < 4; ++i) {
                    int row  = wr * 128 + 64 + i * 16 + lr;
                    int slot = kg ^ ((row >> 1) & 3);
                    a[i] = *(const short8*)&Ak[b][0][row * 32 + slot * 8];
                }
            }
            if (stg) stageB(b ^ 1, 0, wS, kts);
            __builtin_amdgcn_s_barrier();
            asm volatile("s_waitcnt lgkmcnt(0)" ::: "memory");
            __builtin_amdgcn_sched_barrier(0);
            __builtin_amdgcn_s_setprio(1);
            if (alive) {
                #pragma unroll
                for (int i = 0; i < 4; ++i)
                    #pragma unroll
                    for (int nf = 0; nf < 4; ++nf)
                        acc[4 + i][nf] = __builtin_amdgcn_mfma_f32_16x16x32_bf16(a[i], bf[nf], acc[4 + i][nf], 0, 0, 0);
            }
            __builtin_amdgcn_s_setprio(0);
            if (stg) { asm volatile("s_waitcnt vmcnt(4)" ::: "memory"); }
            else     { asm volatile("s_waitcnt vmcnt(0)" ::: "memory"); }
            __builtin_amdgcn_s_barrier();

            // ======== phase 2: ks1, mh0 — reads B.kh1(4) + A.kh1 rows 0-63(4)
            if (alive) {
                #pragma unroll
                for (int i = 0; i < 4; ++i) {
                    int row  = wc * 64 + i * 16 + lr;
                    int slot = kg ^ ((row >> 1) & 3);
                    bf[i] = *(const short8*)&Bk[b][1][row * 32 + slot * 8];
                }
                #pragma unroll
                for (int i = 0; i < 4; ++i) {
                    int row  = wr * 128 + i * 16 + lr;
                    int slot = kg ^ ((row >> 1) & 3);
                    a[i] = *(const short8*)&Ak[b][1][row * 32 + slot * 8];
                }
            }
            if (stg) stageA(b ^ 1, 1, xS, kts);
            __builtin_amdgcn_s_barrier();
            asm volatile("s_waitcnt lgkmcnt(0)" ::: "memory");
            __builtin_amdgcn_sched_barrier(0);
            __builtin_amdgcn_s_setprio(1);
            if (alive) {
                #pragma unroll
                for (int i = 0; i < 4; ++i)
                    #pragma unroll
                    for (int nf = 0; nf < 4; ++nf)
                        acc[i][nf] = __builtin_amdgcn_mfma_f32_16x16x32_bf16(a[i], bf[nf], acc[i][nf], 0, 0, 0);
            }
            __builtin_amdgcn_s_setprio(0);
            __builtin_amdgcn_s_barrier();

            // ======== phase 3: ks1, mh1 — reads A.kh1 rows 64-127(4); bf reused
            if (alive) {
                #pragma unroll
                for (int i = 0; i < 4; ++i) {
                    int row  = wr * 128 + 64 + i * 16 + lr;
                    int slot = kg ^ ((row >> 1) & 3);
                    a[i] = *(const short8*)&Ak[b][1][row * 32 + slot * 8];
                }
            }
            if (stg) stageB(b ^ 1, 1, wS, kts);
            __builtin_amdgcn_s_barrier();
            asm volatile("s_waitcnt lgkmcnt(0)" ::: "memory");
            __builtin_amdgcn_sched_barrier(0);
            __builtin_amdgcn_s_setprio(1);
            if (alive) {
                #pragma unroll
                for (int i = 0; i < 4; ++i)
                    #pragma unroll
                    for (int nf = 0; nf < 4; ++nf)
                        acc[4 + i][nf] = __builtin_amdgcn_mfma_f32_16x16x32_bf16(a[i], bf[nf], acc[4 + i][nf], 0, 0, 0);
            }
            __builtin_amdgcn_s_setprio(0);
            if (stg) { asm volatile("s_waitcnt vmcnt(4)" ::: "memory"); }
            else     { asm volatile("s_waitcnt vmcnt(0)" ::: "memory"); }
            __builtin_amdgcn_s_barrier();
        }

        // epilogue for this slot (overlaps already-issued next-slot prefetch)
        #pragma unroll
        for (int mf = 0; mf < 8; ++mf) {
            int rbase = r0C + wr * 128 + mf * 16 + kg * 4;
            #pragma unroll
            for (int nf = 0; nf < 4; ++nf) {
                int gc = c0C + wc * 64 + nf * 16 + lr;
                #pragma unroll
                for (int q = 0; q < 4; ++q) {
                    int gr = rbase + q;
                    float v = (gr < msC) ? acc[mf][nf][q] : 0.f;
                    oC[(size_t)gr * ND + gc] = v;
                    acc[mf][nf][q] = 0.f;
                }
            }
        }

        // shift slot window
        xC = xN; wC = wN; oC = oN; msC = msN; r0C = r0N; c0C = c0N;
        if (s + 2 < nlive) {
            int v = s_live[s + 2]; int e = v >> 5, br = (v >> 2) & 7, bcl = v & 3;
            r0N = br * BM; c0N = (xcd * 4 + bcl) * BN; msN = ms[e];
            xN = xb + ((size_t)e * MAXM + r0N) * KD;
            wN = wb + ((size_t)e * ND + c0N) * KD;
            oN = out + (size_t)e * MAXM * ND;
        }
    }
}

// ---------------- Fallback: round-1 fused kernel (used only if ws too small) --------
#define FBM 128
#define FBK 32
#define FTM (MAXM/FBM)
#define FTN (ND/FBM)
#define FNT (KD/FBK)
#define LSTR 40
__global__ __launch_bounds__(256, 2) void ggemm_fused(
    const float* __restrict__ x, const float* __restrict__ w,
    const int* __restrict__ ms, float* __restrict__ out)
{
    int nwg  = gridDim.x;
    int orig = blockIdx.x;
    int cpx  = nwg >> 3;
    int bid  = (orig & 7) * cpx + (orig >> 3);
    int e   = bid / (FTM * FTN);
    int rem = bid % (FTM * FTN);
    int br  = rem % FTM;
    int bc  = rem / FTM;
    int m_size = ms[e];
    int row0 = br * FBM, col0 = bc * FBM;
    float* outE = out + (size_t)e * MAXM * ND;
    int tid = threadIdx.x;

    if (row0 >= m_size) {
        f32x4 z = (f32x4){0.f, 0.f, 0.f, 0.f};
        #pragma unroll
        for (int q = 0; q < 16; ++q) {
            int i2 = tid + q * 256;
            int rr = i2 >> 5, cc = (i2 & 31) << 2;
            *(f32x4*)(outE + (size_t)(row0 + rr) * ND + col0 + cc) = z;
        }
        return;
    }

    const float* xE = x + ((size_t)e * MAXM + row0) * KD;
    const float* wE = w + ((size_t)e * ND   + col0) * KD;

    __shared__ unsigned short As[2][FBM][LSTR];
    __shared__ unsigned short Bs[2][FBM][LSTR];

    int sr  = tid >> 3;
    int sc4 = tid & 7;
    int wid = tid >> 6, lane = tid & 63;
    int wr = wid >> 1, wc = wid & 1;
    int lr = lane & 15, kg = lane >> 4;

    f32x4 acc[4][4];
    #pragma unroll
    for (int m = 0; m < 4; ++m)
        #pragma unroll
        for (int n = 0; n < 4; ++n)
            acc[m][n] = (f32x4){0.f, 0.f, 0.f, 0.f};

    {
        #pragma unroll
        for (int q = 0; q < 4; ++q) {
            int r0 = sr + q * 32;
            f32x4 av = *(const f32x4*)(xE + (size_t)r0 * KD + sc4 * 4);
            f32x4 bv = *(const f32x4*)(wE + (size_t)r0 * KD + sc4 * 4);
            us4 ah = (us4){f2bf(av[0]), f2bf(av[1]), f2bf(av[2]), f2bf(av[3])};
            us4 bh = (us4){f2bf(bv[0]), f2bf(bv[1]), f2bf(bv[2]), f2bf(bv[3])};
            *(us4*)&As[0][r0][sc4 * 4] = ah;
            *(us4*)&Bs[0][r0][sc4 * 4] = bh;
        }
    }
    __syncthreads();

    for (int t = 0; t < FNT; ++t) {
        int cur = t & 1;
        f32x4 av[4], bv[4];
        bool pre = (t + 1 < FNT);
        if (pre) {
            const float* xk = xE + (size_t)(t + 1) * FBK;
            const float* wk = wE + (size_t)(t + 1) * FBK;
            #pragma unroll
            for (int q = 0; q < 4; ++q) {
                int r0 = sr + q * 32;
                av[q] = *(const f32x4*)(xk + (size_t)r0 * KD + sc4 * 4);
                bv[q] = *(const f32x4*)(wk + (size_t)r0 * KD + sc4 * 4);
            }
        }
        short8 a[4], b[4];
        #pragma unroll
        for (int m = 0; m < 4; ++m)
            a[m] = *(const short8*)&As[cur][wr * 64 + m * 16 + lr][kg * 8];
        #pragma unroll
        for (int n = 0; n < 4; ++n)
            b[n] = *(const short8*)&Bs[cur][wc * 64 + n * 16 + lr][kg * 8];
        #pragma unroll
        for (int m = 0; m < 4; ++m)
            #pragma unroll
            for (int n = 0; n < 4; ++n)
                acc[m][n] = __builtin_amdgcn_mfma_f32_16x16x32_bf16(a[m], b[n], acc[m][n], 0, 0, 0);

        if (pre) {
            int nb = cur ^ 1;
            #pragma unroll
            for (int q = 0; q < 4; ++q) {
                int r0 = sr + q * 32;
                us4 ah = (us4){f2bf(av[q][0]), f2bf(av[q][1]), f2bf(av[q][2]), f2bf(av[q][3])};
                us4 bh = (us4){f2bf(bv[q][0]), f2bf(bv[q][1]), f2bf(bv[q][2]), f2bf(bv[q][3])};
                *(us4*)&As[nb][r0][sc4 * 4] = ah;
                *(us4*)&Bs[nb][r0][sc4 * 4] = bh;
            }
        }
        __syncthreads();
    }

    #pragma unroll
    for (int m = 0; m < 4; ++m) {
        int rbase = row0 + wr * 64 + m * 16 + kg * 4;
        #pragma unroll
        for (int n = 0; n < 4; ++n) {
            int gc = col0 + wc * 64 + n * 16 + lr;
            #pragma unroll
            for (int q = 0; q < 4; ++q) {
                int gr = rbase + q;
                float v = (gr < m_size) ? acc[m][n][q] : 0.f;
                outE[(size_t)gr * ND + gc] = v;
            }
        }
    }
}

extern "C" void kernel_launch(void* const* d_in, const int* in_sizes, int n_in,
                              void* d_out, int out_size, void* d_ws, size_t ws_size,
                              hipStream_t stream) {
    const float* x  = (const float*)d_in[0];
    const float* w  = (const float*)d_in[1];
    const int*   ms = (const int*)d_in[2];
    float* out = (float*)d_out;

    const size_t xElems = (size_t)NE * MAXM * KD;   // 33,554,432
    const size_t wElems = (size_t)NE * ND   * KD;   // 134,217,728
    const size_t need   = (xElems + wElems) * 2;    // 335,544,320 B

    if (ws_size >= need) {
        unsigned short* xb = (unsigned short*)d_ws;
        unsigned short* wb = xb + xElems;
        cvt_x_kernel<<<NE * MAXM, 256, 0, stream>>>(x, xb, ms);
        cvt_kernel<<<2048, 256, 0, stream>>>(w, wb, (int)(wElems / 8));
        ggemm_pers<<<256, 512, 0, stream>>>(xb, wb, ms, out);
    } else {
        ggemm_fused<<<dim3(NE * (MAXM/FBM) * (ND/FBM)), dim3(256), 0, stream>>>(x, w, ms, out);
    }
}